// Round 12
// baseline (43.623 us; speedup 1.0000x reference)
//
#include <hip/hip_runtime.h>

// LIF forward scan, B=65536 rows x L=400 steps.
// Outputs (concatenated float32 in d_out):
//   [0,              B*L)    spikes (exactly 0.0/1.0)
//   [B*L,        B*L + B)    hard_latency (first spike index, or L) as float
//   [B*L + B,  B*L + 2*B)    soft_latency = sum(s*t) / (sum(s) + 1e-6)
//
// R11: producer-consumer (2 waves/block) with PAIR-level phases (80 steps):
//  - 6 barriers/block (was 11): each phase's compute ~2000cyc > HBM latency,
//    so the memory wave's pre-barrier vmcnt(0) drain hides under the scan.
//  - memory wave loads are COALESCED (lane -> linear tile index, ~17
//    lines/inst instead of 64 for the per-row gather).
//  - input staged at stride 81 (2 lanes/bank -> conflict-free), spikes cross
//    waves as bits, cnt/swt/first via popcount/ffs (integer-exact).

constexpr int Bsz   = 65536;
constexpr int Lsz   = 400;
constexpr int ROWS  = 64;           // rows per block (one per compute lane)
constexpr int PW    = 80;           // steps per pair (phase)
constexpr int NPAIR = 5;
constexpr int STRIDE = 81;          // 17*l mod 32 all-distinct -> 2 lanes/bank

typedef float floatx4 __attribute__((ext_vector_type(4)));

__device__ __forceinline__ int sumpos(unsigned int w) {
    // sum of set-bit positions within a 32-bit word (exact)
    return __popc(w & 0xAAAAAAAAu) + (__popc(w & 0xCCCCCCCCu) << 1) +
           (__popc(w & 0xF0F0F0F0u) << 2) + (__popc(w & 0xFF00FF00u) << 3) +
           (__popc(w & 0xFFFF0000u) << 4);
}

__global__ __launch_bounds__(2 * ROWS)
void lif_kernel(const float* __restrict__ I, float* __restrict__ out)
{
    __shared__ float in2[2][ROWS * STRIDE];        // 41,472 B input staging
    __shared__ unsigned int bits[2][ROWS * 4];     // 2 KiB spike bits

    const int tid  = threadIdx.x;
    const int wv   = tid >> 6;       // 0 = compute wave, 1 = memory wave
    const int lane = tid & 63;
    const int rb   = blockIdx.x * ROWS;

    if (wv == 1) {
        // ------------------------- memory wave -------------------------
        const float* Ib = I   + (size_t)rb * Lsz;
        float*       Sb = out + (size_t)rb * Lsz;
        float4 rg[20];               // one pair (64 rows x 320B), lane-linear

        auto issue = [&](int p) {    // coalesced: idx=k*64+lane, ~17 lines/inst
#pragma unroll
            for (int k = 0; k < 20; ++k) {
                const int idx = k * 64 + lane;
                const int r   = idx / 20;
                const int c4  = idx % 20;
                rg[k] = *reinterpret_cast<const float4*>(
                            Ib + (size_t)r * Lsz + p * PW + c4 * 4);
            }
        };
        auto put = [&](float* buf) { // rg -> stride-81 tile (b32, ~2-3/bank)
#pragma unroll
            for (int k = 0; k < 20; ++k) {
                const int idx = k * 64 + lane;
                const int r   = idx / 20;
                const int c4  = idx % 20;
                float* d = &buf[r * STRIDE + c4 * 4];
                d[0] = rg[k].x; d[1] = rg[k].y; d[2] = rg[k].z; d[3] = rg[k].w;
            }
        };
        auto expand = [&](int p) {   // bits -> dense NT float4 stores
            const unsigned int* bl = bits[p & 1];
#pragma unroll
            for (int k = 0; k < 20; ++k) {
                const int idx = k * 64 + lane;
                const int r   = idx / 20;
                const int c4  = idx % 20;
                const unsigned int w = bl[r * 4 + (c4 >> 3)];
                const int bb = (c4 & 7) * 4;
                floatx4 vv = { (float)((w >> (bb + 0)) & 1u),
                               (float)((w >> (bb + 1)) & 1u),
                               (float)((w >> (bb + 2)) & 1u),
                               (float)((w >> (bb + 3)) & 1u) };
                __builtin_nontemporal_store(vv,
                    reinterpret_cast<floatx4*>(Sb + (size_t)r * Lsz + p * PW + c4 * 4));
            }
        };

        issue(0);                    // pair 0 loads (full-latency wait, once)
        put(in2[0]);
        issue(1);                    // pair 1 in flight; drained at barrier
        __syncthreads();
        for (int pr = 0; pr < NPAIR; ++pr) {
            if (pr + 1 < NPAIR) put(in2[(pr + 1) & 1]);  // loads drained last barrier
            if (pr + 2 < NPAIR) issue(pr + 2);           // reuse rg; ~2k cyc cover
            if (pr >= 1) expand(pr - 1);
            __syncthreads();
        }
        expand(NPAIR - 1);
    } else {
        // ------------------------- compute wave ------------------------
        float v = 0.0f, theta = 1.0f;
        int allow = 0, first = Lsz;
        int cnt_i = 0, swt_i = 0;
        unsigned int w0, w1, w2;
        float rgc[40];

        auto scan40 = [&](const float* src, int t0, int gb) {
#pragma unroll
            for (int c = 0; c < 40; ++c) rgc[c] = src[c];   // batch LDS->reg
#pragma unroll
            for (int c = 0; c < 40; ++c) {
                v = __builtin_fmaf(v, 0.95f, rgc[c]);       // v += -v/20 + I
                const int t = t0 + c;
                const bool hard = (v >= theta) & (t >= allow);
                v     = hard ? 0.0f : v;
                theta = __builtin_fmaf(theta, 0.98f, hard ? 0.52f : 0.02f);
                allow = hard ? (t + 6) : allow;             // 5 blocked steps
                const int cg = gb + c;                      // compile-time
                const unsigned int m = hard ? (1u << (cg & 31)) : 0u;
                if (cg < 32) w0 |= m; else if (cg < 64) w1 |= m; else w2 |= m;
            }
        };

        __syncthreads();             // matches memory prologue barrier
        for (int pr = 0; pr < NPAIR; ++pr) {
            const float* src = &in2[pr & 1][lane * STRIDE];
            w0 = w1 = w2 = 0u;
            scan40(src,      pr * PW,      0);
            scan40(src + 40, pr * PW + 40, 40);
            // pair-end reductions (exact) + publish bits
            const int tp = pr * PW;
            const int p0 = __popc(w0), p1 = __popc(w1), p2 = __popc(w2);
            const int cp = p0 + p1 + p2;
            cnt_i += cp;
            swt_i += tp * cp + sumpos(w0) + sumpos(w1) + 32 * p1 +
                     sumpos(w2) + 64 * p2;
            const int cand = w0 ? tp + (__ffs(w0) - 1)
                           : w1 ? tp + 32 + (__ffs(w1) - 1)
                           : w2 ? tp + 64 + (__ffs(w2) - 1) : Lsz;
            first = min(first, cand);
            *reinterpret_cast<uint4*>(&bits[pr & 1][lane * 4]) =
                make_uint4(w0, w1, w2, 0u);
            __syncthreads();
        }
        const int row = rb + lane;
        out[(size_t)Bsz * Lsz + row]       = (float)first;
        out[(size_t)Bsz * Lsz + Bsz + row] = (float)swt_i / ((float)cnt_i + 1e-6f);
    }
}

extern "C" void kernel_launch(void* const* d_in, const int* in_sizes, int n_in,
                              void* d_out, int out_size, void* d_ws, size_t ws_size,
                              hipStream_t stream)
{
    const float* I = (const float*)d_in[0];
    float* out = (float*)d_out;
    lif_kernel<<<dim3(Bsz / ROWS), dim3(2 * ROWS), 0, stream>>>(I, out);
}